// Round 1
// baseline (295.268 us; speedup 1.0000x reference)
//
#include <hip/hip_runtime.h>
#include <math.h>

#define BATCH 128
#define CHN   128
#define HW    256            // 16*16
#define PLANE (CHN*HW)       // per-image elements = 32768
#define TOTAL (BATCH*CHN*HW) // 4194304
#define WELEM (CHN*CHN*9)    // 147456

// ---- ws layout (bytes) ----
// 0        : 2 x uint  (max|tanh(w)| bits, w1/w2)
// 1024     : stats1 (mean,inv_std interleaved, 256 floats)
// 2048     : stats2
// 4096     : wq1_t  [ic][tap][oc]  147456 floats
// 593920   : wq2_t  147456 floats
// 1183744  : h codes (u8, 4194304) -- reused for h1 then h2
// end ~5.4 MB

__device__ __forceinline__ float wave_sum(float v) {
    #pragma unroll
    for (int off = 32; off; off >>= 1) v += __shfl_down(v, off, 64);
    return v;
}
__device__ __forceinline__ float wave_max(float v) {
    #pragma unroll
    for (int off = 32; off; off >>= 1) v = fmaxf(v, __shfl_down(v, off, 64));
    return v;
}

// per-channel mean / inv_std over (N,H,W): one block per channel
extern "C" __global__ void __launch_bounds__(256)
k_stats(const float* __restrict__ src, float* __restrict__ stats) {
    int c = blockIdx.x;
    int t = threadIdx.x;
    const float* p = src + c * HW + t;
    float s = 0.f, s2 = 0.f;
    #pragma unroll 4
    for (int n = 0; n < BATCH; ++n) {
        float v = p[n * PLANE];
        s += v; s2 += v * v;
    }
    s = wave_sum(s); s2 = wave_sum(s2);
    __shared__ float ls[8];
    int lane = t & 63, wid = t >> 6;
    if (lane == 0) { ls[wid] = s; ls[4 + wid] = s2; }
    __syncthreads();
    if (t == 0) {
        float S  = ls[0] + ls[1] + ls[2] + ls[3];
        float S2 = ls[4] + ls[5] + ls[6] + ls[7];
        float mean = S * (1.f / 32768.f);
        float var  = S2 * (1.f / 32768.f) - mean * mean;
        stats[2 * c]     = mean;
        stats[2 * c + 1] = 1.0f / sqrtf(var + 1e-5f);
    }
}

// global max |tanh(w)| for both weight tensors (blockIdx.y selects)
extern "C" __global__ void __launch_bounds__(256)
k_wmax(const float* __restrict__ w1, const float* __restrict__ w2,
       unsigned* __restrict__ wmax) {
    const float* w = blockIdx.y ? w2 : w1;
    int t = threadIdx.x;
    int i = blockIdx.x * 2048 + t;   // 72 blocks * 2048 = 147456 exactly
    float m = 0.f;
    #pragma unroll
    for (int k = 0; k < 8; ++k)
        m = fmaxf(m, fabsf(tanhf(w[i + k * 256])));
    m = wave_max(m);
    __shared__ float ls[4];
    int lane = t & 63, wid = t >> 6;
    if (lane == 0) ls[wid] = m;
    __syncthreads();
    if (t == 0) {
        float mm = fmaxf(fmaxf(ls[0], ls[1]), fmaxf(ls[2], ls[3]));
        atomicMax(wmax + blockIdx.y, __float_as_uint(mm)); // >=0 floats: bit order preserved
    }
}

// DoReFa weight quant + pattern mask, transposed to [ic][tap][oc] (coalesced writes)
extern "C" __global__ void __launch_bounds__(256)
k_wquant(const float* __restrict__ w1, const float* __restrict__ w2,
         const float* __restrict__ pat1, const float* __restrict__ pat2,
         const unsigned* __restrict__ wmax,
         float* __restrict__ wq1, float* __restrict__ wq2) {
    int y = blockIdx.y;
    const float* w   = y ? w2 : w1;
    const float* pat = y ? pat2 : pat1;
    float* wq        = y ? wq2 : wq1;
    float M = __uint_as_float(wmax[y]);
    int i = blockIdx.x * 256 + threadIdx.x;   // enumerates (ic, tap, oc)
    int oc = i & 127;
    int ictap = i >> 7;
    int ic = ictap / 9, tap = ictap % 9;
    float tv = tanhf(w[(oc * CHN + ic) * 9 + tap]);
    float tn = tv / (2.0f * M) + 0.5f;
    float q  = rintf(tn * 15.f);
    wq[i] = (q * (2.f / 15.f) - 1.f) * pat[tap];
}

// BN + clip[0,1] + 4-bit quant -> u8 code (value = code/15)
extern "C" __global__ void __launch_bounds__(256)
k_act(const float* __restrict__ src, const float* __restrict__ stats,
      const float* __restrict__ gamma, const float* __restrict__ beta,
      unsigned char* __restrict__ dst) {
    int i = blockIdx.x * 256 + threadIdx.x;  // 4 elements per thread
    int base = i << 2;
    int c = (base >> 8) & 127;
    float mean = stats[2 * c], istd = stats[2 * c + 1];
    float sc = istd * gamma[c];
    float sh = beta[c] - mean * sc;
    float4 v = *(const float4*)(src + base);
    uchar4 o;
    o.x = (unsigned char)(int)rintf(fminf(fmaxf(v.x * sc + sh, 0.f), 1.f) * 15.f);
    o.y = (unsigned char)(int)rintf(fminf(fmaxf(v.y * sc + sh, 0.f), 1.f) * 15.f);
    o.z = (unsigned char)(int)rintf(fminf(fmaxf(v.z * sc + sh, 0.f), 1.f) * 15.f);
    o.w = (unsigned char)(int)rintf(fminf(fmaxf(v.w * sc + sh, 0.f), 1.f) * 15.f);
    *(uchar4*)(dst + base) = o;
}

// direct 3x3 conv, pad 1: block = (1 image, 16 out-channels), thread = 1 pixel
extern "C" __global__ void __launch_bounds__(256)
k_conv(const unsigned char* __restrict__ act, const float* __restrict__ wq_t,
       const float* __restrict__ pat, const float* __restrict__ xres,
       float* __restrict__ out) {
    int n   = blockIdx.x;
    int oc0 = blockIdx.y << 4;
    int t   = threadIdx.x;
    int h = t >> 4, w = t & 15;

    __shared__ float in_lds[18 * 18];
    __shared__ float w_lds[9 * 16];

    // zero the halo once (interior rewritten every ic)
    in_lds[t] = 0.f;
    if (t < 324 - 256) in_lds[t + 256] = 0.f;

    bool pf[9];
    #pragma unroll
    for (int j = 0; j < 9; ++j) pf[j] = (pat[j] != 0.f);

    float acc[16];
    #pragma unroll
    for (int o = 0; o < 16; ++o) acc[o] = 0.f;

    const int center = (h + 1) * 18 + (w + 1);
    __syncthreads();

    for (int ic = 0; ic < CHN; ++ic) {
        in_lds[center] = (float)act[(n * CHN + ic) * HW + t] * (1.f / 15.f);
        if (t < 144) w_lds[t] = wq_t[(ic * 9 + (t >> 4)) * CHN + oc0 + (t & 15)];
        __syncthreads();

        #pragma unroll
        for (int kh = 0; kh < 3; ++kh) {
            #pragma unroll
            for (int kw = 0; kw < 3; ++kw) {
                const int tap = kh * 3 + kw;
                if (pf[tap]) {   // uniform branch: skip masked taps
                    float vv = in_lds[(h + kh) * 18 + (w + kw)];
                    const float4 wa = *(const float4*)&w_lds[tap * 16];
                    const float4 wb = *(const float4*)&w_lds[tap * 16 + 4];
                    const float4 wc = *(const float4*)&w_lds[tap * 16 + 8];
                    const float4 wd = *(const float4*)&w_lds[tap * 16 + 12];
                    acc[0]  += vv * wa.x; acc[1]  += vv * wa.y;
                    acc[2]  += vv * wa.z; acc[3]  += vv * wa.w;
                    acc[4]  += vv * wb.x; acc[5]  += vv * wb.y;
                    acc[6]  += vv * wb.z; acc[7]  += vv * wb.w;
                    acc[8]  += vv * wc.x; acc[9]  += vv * wc.y;
                    acc[10] += vv * wc.z; acc[11] += vv * wc.w;
                    acc[12] += vv * wd.x; acc[13] += vv * wd.y;
                    acc[14] += vv * wd.z; acc[15] += vv * wd.w;
                }
            }
        }
        __syncthreads();
    }

    #pragma unroll
    for (int o = 0; o < 16; ++o) {
        int idx = (n * CHN + oc0 + o) * HW + t;
        float val = acc[o];
        if (xres) val += xres[idx];
        out[idx] = val;
    }
}

extern "C" void kernel_launch(void* const* d_in, const int* in_sizes, int n_in,
                              void* d_out, int out_size, void* d_ws, size_t ws_size,
                              hipStream_t stream) {
    const float* x      = (const float*)d_in[0];
    const float* gamma1 = (const float*)d_in[1];
    const float* beta1  = (const float*)d_in[2];
    const float* gamma2 = (const float*)d_in[3];
    const float* beta2  = (const float*)d_in[4];
    const float* w1     = (const float*)d_in[5];
    const float* w2     = (const float*)d_in[6];
    const float* pat1   = (const float*)d_in[7];
    const float* pat2   = (const float*)d_in[8];
    float* out = (float*)d_out;

    char* ws = (char*)d_ws;
    unsigned* wmax  = (unsigned*)(ws + 0);
    float* stats1   = (float*)(ws + 1024);
    float* stats2   = (float*)(ws + 2048);
    float* wq1      = (float*)(ws + 4096);
    float* wq2      = (float*)(ws + 593920);
    unsigned char* hbuf = (unsigned char*)(ws + 1183744);

    hipMemsetAsync(wmax, 0, 8, stream);
    k_wmax<<<dim3(72, 2), 256, 0, stream>>>(w1, w2, wmax);
    k_wquant<<<dim3(WELEM / 256, 2), 256, 0, stream>>>(w1, w2, pat1, pat2, wmax, wq1, wq2);

    // h1 = act_quant(bn1(x))
    k_stats<<<128, 256, 0, stream>>>(x, stats1);
    k_act<<<TOTAL / 4 / 256, 256, 0, stream>>>(x, stats1, gamma1, beta1, hbuf);
    // conv1 -> d_out (scratch)
    k_conv<<<dim3(BATCH, 8), 256, 0, stream>>>(hbuf, wq1, pat1, nullptr, out);
    // h2 = act_quant(bn2(out1))
    k_stats<<<128, 256, 0, stream>>>(out, stats2);
    k_act<<<TOTAL / 4 / 256, 256, 0, stream>>>(out, stats2, gamma2, beta2, hbuf);
    // conv2 + residual -> d_out (final)
    k_conv<<<dim3(BATCH, 8), 256, 0, stream>>>(hbuf, wq2, pat2, x, out);
}

// Round 2
// 84.784 us; speedup vs baseline: 3.4826x; 3.4826x over previous
//
#include <hip/hip_runtime.h>
#include <math.h>

#define BATCH 128
#define CHN   128
#define HW    256            // 16*16
#define PLANE (CHN*HW)       // 32768
#define WELEM (CHN*CHN*9)    // 147456

using int4v  = __attribute__((ext_vector_type(4))) int;
using int16v = __attribute__((ext_vector_type(16))) int;

// ---- ws layout (bytes) ----
// 0       : 2 x uint (max|tanh(w)| bits)
// 1024    : stats1 (mean,inv_std interleaved)
// 2048    : stats2
// 4096    : wq1 i8, MFMA-fragment order, 147456 B
// 151552  : wq2 i8, 147456 B
// 299008  : hbufT u8 [n][p][c], 4194304 B   (end ~4.5 MB)

__device__ __forceinline__ float wave_sum(float v) {
    #pragma unroll
    for (int off = 32; off; off >>= 1) v += __shfl_down(v, off, 64);
    return v;
}
__device__ __forceinline__ float wave_max(float v) {
    #pragma unroll
    for (int off = 32; off; off >>= 1) v = fmaxf(v, __shfl_down(v, off, 64));
    return v;
}

// per-channel mean / inv_std over (N,H,W): one block per channel
extern "C" __global__ void __launch_bounds__(256)
k_stats(const float* __restrict__ src, float* __restrict__ stats) {
    int c = blockIdx.x;
    int t = threadIdx.x;
    const float* p = src + c * HW + t;
    float s = 0.f, s2 = 0.f;
    #pragma unroll 4
    for (int n = 0; n < BATCH; ++n) {
        float v = p[n * PLANE];
        s += v; s2 += v * v;
    }
    s = wave_sum(s); s2 = wave_sum(s2);
    __shared__ float ls[8];
    int lane = t & 63, wid = t >> 6;
    if (lane == 0) { ls[wid] = s; ls[4 + wid] = s2; }
    __syncthreads();
    if (t == 0) {
        float S  = ls[0] + ls[1] + ls[2] + ls[3];
        float S2 = ls[4] + ls[5] + ls[6] + ls[7];
        float mean = S * (1.f / 32768.f);
        float var  = S2 * (1.f / 32768.f) - mean * mean;
        stats[2 * c]     = mean;
        stats[2 * c + 1] = 1.0f / sqrtf(var + 1e-5f);
    }
}

// global max |tanh(w)| for both weight tensors
extern "C" __global__ void __launch_bounds__(256)
k_wmax(const float* __restrict__ w1, const float* __restrict__ w2,
       unsigned* __restrict__ wmax) {
    const float* w = blockIdx.y ? w2 : w1;
    int t = threadIdx.x;
    int i = blockIdx.x * 2048 + t;   // 72 blocks * 2048 = 147456
    float m = 0.f;
    #pragma unroll
    for (int k = 0; k < 8; ++k)
        m = fmaxf(m, fabsf(tanhf(w[i + k * 256])));
    m = wave_max(m);
    __shared__ float ls[4];
    int lane = t & 63, wid = t >> 6;
    if (lane == 0) ls[wid] = m;
    __syncthreads();
    if (t == 0) {
        float mm = fmaxf(fmaxf(ls[0], ls[1]), fmaxf(ls[2], ls[3]));
        atomicMax(wmax + blockIdx.y, __float_as_uint(mm));
    }
}

// DoReFa weight quant + pattern mask -> i8 laid out in MFMA fragment order:
// byte index = ((ocb*4608 + tap*512 + q*128 + m*64 + hq*32 + l31)*16 + j)
// holding w_int[oc=ocb*64+m*32+l31][tap][ic=q*32+hq*16+j]
extern "C" __global__ void __launch_bounds__(256)
k_wquant(const float* __restrict__ w1, const float* __restrict__ w2,
         const float* __restrict__ pat1, const float* __restrict__ pat2,
         const unsigned* __restrict__ wmax,
         signed char* __restrict__ wq1, signed char* __restrict__ wq2) {
    int y = blockIdx.y;
    const float* w   = y ? w2 : w1;
    const float* pat = y ? pat2 : pat1;
    signed char* wq  = y ? wq2 : wq1;
    float M = __uint_as_float(wmax[y]);
    int i = blockIdx.x * 256 + threadIdx.x;  // 0 .. 147455
    int j = i & 15;
    int c = i >> 4;
    int ocb = (c >= 4608) ? 1 : 0;
    int rem = c - ocb * 4608;
    int tap = rem >> 9;
    int q   = (rem >> 7) & 3;
    int m   = (rem >> 6) & 1;
    int hq  = (rem >> 5) & 1;
    int l31 = rem & 31;
    int oc = ocb * 64 + m * 32 + l31;
    int ic = q * 32 + hq * 16 + j;
    float tv = tanhf(w[(oc * CHN + ic) * 9 + tap]);
    float tn = tv / (2.0f * M) + 0.5f;
    int mq = (int)rintf(tn * 15.f);
    mq = mq < 0 ? 0 : (mq > 15 ? 15 : mq);
    int qv = 2 * mq - 15;
    if (pat[tap] == 0.f) qv = 0;
    wq[i] = (signed char)qv;
}

// BN + clip + 4-bit quant + transpose to [n][p][c] u8 codes.
// block = half an image (128 pixels); LDS word-transpose, stride 129 (conflict-free)
extern "C" __global__ void __launch_bounds__(256)
k_actT(const float* __restrict__ src, const float* __restrict__ stats,
       const float* __restrict__ gamma, const float* __restrict__ beta,
       unsigned char* __restrict__ dstT) {
    int b = blockIdx.x;
    int n = b >> 1, half = b & 1;
    int t = threadIdx.x;
    __shared__ unsigned int tmp[32 * 129];

    const float* sp = src + (size_t)n * PLANE + half * 128;
    #pragma unroll 4
    for (int j = 0; j < 16; ++j) {
        int id = j * 256 + t;            // c = id>>5 (0..127), p4 = id&31
        int cch = id >> 5, p4 = id & 31;
        float sc = stats[2 * cch + 1] * gamma[cch];
        float sh = beta[cch] - stats[2 * cch] * sc;
        float4 v = *(const float4*)(sp + cch * HW + p4 * 4);
        unsigned q0 = (unsigned)(int)rintf(fminf(fmaxf(v.x * sc + sh, 0.f), 1.f) * 15.f);
        unsigned q1 = (unsigned)(int)rintf(fminf(fmaxf(v.y * sc + sh, 0.f), 1.f) * 15.f);
        unsigned q2 = (unsigned)(int)rintf(fminf(fmaxf(v.z * sc + sh, 0.f), 1.f) * 15.f);
        unsigned q3 = (unsigned)(int)rintf(fminf(fmaxf(v.w * sc + sh, 0.f), 1.f) * 15.f);
        tmp[p4 * 129 + cch] = q0 | (q1 << 8) | (q2 << 16) | (q3 << 24);
    }
    __syncthreads();

    unsigned char* dp = dstT + (size_t)n * PLANE + half * 128 * CHN;
    {
        int p4 = t & 31, c0 = (t >> 5) << 4;   // 32 p4-groups x 8 c-chunks
        unsigned w[16];
        #pragma unroll
        for (int k = 0; k < 16; ++k) w[k] = tmp[p4 * 129 + c0 + k];
        #pragma unroll
        for (int pp = 0; pp < 4; ++pp) {
            int s = pp * 8;
            int4v o;
            o.x = (int)(((w[0] >> s) & 255u) | (((w[1] >> s) & 255u) << 8) |
                        (((w[2] >> s) & 255u) << 16) | (((w[3] >> s) & 255u) << 24));
            o.y = (int)(((w[4] >> s) & 255u) | (((w[5] >> s) & 255u) << 8) |
                        (((w[6] >> s) & 255u) << 16) | (((w[7] >> s) & 255u) << 24));
            o.z = (int)(((w[8] >> s) & 255u) | (((w[9] >> s) & 255u) << 8) |
                        (((w[10] >> s) & 255u) << 16) | (((w[11] >> s) & 255u) << 24));
            o.w = (int)(((w[12] >> s) & 255u) | (((w[13] >> s) & 255u) << 8) |
                        (((w[14] >> s) & 255u) << 16) | (((w[15] >> s) & 255u) << 24));
            *(int4v*)(dp + (p4 * 4 + pp) * 128 + c0) = o;
        }
    }
}

// i8 MFMA conv: block = (image, oc-half), 4 waves, wave tile = 64oc x 64px
extern "C" __global__ void __launch_bounds__(256, 1)
k_conv(const unsigned char* __restrict__ actT,   // [n][p][c] codes
       const signed char*  __restrict__ wq,      // fragment-ordered i8
       const float* __restrict__ pat,
       const float* __restrict__ xres,
       float* __restrict__ out) {
    int n = blockIdx.x, ocb = blockIdx.y;
    int t = threadIdx.x;
    int lane = t & 63, wid = t >> 6;
    int l31 = lane & 31, hq = lane >> 5;

    __shared__ __align__(16) unsigned char lds[41472 + 73728];
    unsigned char* A = lds;            // padded act [r=18*18][128], swizzled
    unsigned char* W = lds + 41472;    // fragment-ordered weights (this oc-half)

    // zero act buffer (incl halo)
    int4v z; z.x = 0; z.y = 0; z.z = 0; z.w = 0;
    for (int i = t; i < 2592; i += 256) *(int4v*)(A + i * 16) = z;
    __syncthreads();

    // stage weights: straight coalesced copy (fragment order already)
    {
        const int4v* wsrc = (const int4v*)(wq + (size_t)ocb * 73728);
        int4v* wdst = (int4v*)W;
        #pragma unroll
        for (int j = 0; j < 18; ++j) wdst[j * 256 + t] = wsrc[j * 256 + t];
    }
    // stage activations: coalesced dwordx4 -> XOR-swizzled LDS rows
    {
        const unsigned char* ap = actT + (size_t)n * PLANE;
        #pragma unroll
        for (int j = 0; j < 8; ++j) {
            int id = j * 256 + t;
            int p = id >> 3, c0 = (id & 7) << 4;
            int r = ((p >> 4) + 1) * 18 + (p & 15) + 1;
            int4v v = *(const int4v*)(ap + p * 128 + c0);
            *(int4v*)(A + r * 128 + (c0 ^ ((r & 7) << 4))) = v;
        }
    }
    __syncthreads();

    int16v acc[2][2];
    #pragma unroll
    for (int m = 0; m < 2; ++m)
        #pragma unroll
        for (int nn = 0; nn < 2; ++nn)
            #pragma unroll
            for (int e = 0; e < 16; ++e) acc[m][nn][e] = 0;

    int p0 = wid * 64 + l31;
    int h0 = p0 >> 4, w0c = p0 & 15;
    int p1 = p0 + 32;
    int h1 = p1 >> 4, w1c = p1 & 15;
    int cbase = hq * 16;

    #pragma unroll
    for (int tap = 0; tap < 9; ++tap) {
        if (pat[tap] != 0.f) {
            int dy = tap / 3, dx = tap % 3;
            int r0 = (h0 + dy) * 18 + (w0c + dx);
            int r1 = (h1 + dy) * 18 + (w1c + dx);
            int b0base = r0 * 128 + (cbase ^ ((r0 & 7) << 4));
            int b1base = r1 * 128 + (cbase ^ ((r1 & 7) << 4));
            const unsigned char* wt = W + tap * 8192 + lane * 16;
            #pragma unroll
            for (int q = 0; q < 4; ++q) {
                int4v a0 = *(const int4v*)(wt + q * 2048);
                int4v a1 = *(const int4v*)(wt + q * 2048 + 1024);
                int4v b0 = *(const int4v*)(A + (b0base ^ (q << 5)));
                int4v b1 = *(const int4v*)(A + (b1base ^ (q << 5)));
                acc[0][0] = __builtin_amdgcn_mfma_i32_32x32x32_i8(a0, b0, acc[0][0], 0, 0, 0);
                acc[0][1] = __builtin_amdgcn_mfma_i32_32x32x32_i8(a0, b1, acc[0][1], 0, 0, 0);
                acc[1][0] = __builtin_amdgcn_mfma_i32_32x32x32_i8(a1, b0, acc[1][0], 0, 0, 0);
                acc[1][1] = __builtin_amdgcn_mfma_i32_32x32x32_i8(a1, b1, acc[1][1], 0, 0, 0);
            }
        }
    }

    float* ob = out + ((size_t)n * CHN + ocb * 64) * HW;
    const float* xb = xres ? xres + ((size_t)n * CHN + ocb * 64) * HW : (const float*)0;
    #pragma unroll
    for (int m = 0; m < 2; ++m)
        #pragma unroll
        for (int nn = 0; nn < 2; ++nn) {
            int p = wid * 64 + nn * 32 + l31;
            #pragma unroll
            for (int e = 0; e < 16; ++e) {
                int row = (e & 3) + 8 * (e >> 2) + 4 * hq;
                int idx = (m * 32 + row) * HW + p;
                float v = (float)acc[m][nn][e] * (1.f / 225.f);
                if (xb) v += xb[idx];
                ob[idx] = v;
            }
        }
}

extern "C" void kernel_launch(void* const* d_in, const int* in_sizes, int n_in,
                              void* d_out, int out_size, void* d_ws, size_t ws_size,
                              hipStream_t stream) {
    const float* x      = (const float*)d_in[0];
    const float* gamma1 = (const float*)d_in[1];
    const float* beta1  = (const float*)d_in[2];
    const float* gamma2 = (const float*)d_in[3];
    const float* beta2  = (const float*)d_in[4];
    const float* w1     = (const float*)d_in[5];
    const float* w2     = (const float*)d_in[6];
    const float* pat1   = (const float*)d_in[7];
    const float* pat2   = (const float*)d_in[8];
    float* out = (float*)d_out;

    char* ws = (char*)d_ws;
    unsigned* wmax   = (unsigned*)(ws + 0);
    float* stats1    = (float*)(ws + 1024);
    float* stats2    = (float*)(ws + 2048);
    signed char* wq1 = (signed char*)(ws + 4096);
    signed char* wq2 = (signed char*)(ws + 151552);
    unsigned char* hbufT = (unsigned char*)(ws + 299008);

    hipMemsetAsync(wmax, 0, 8, stream);
    k_wmax<<<dim3(72, 2), 256, 0, stream>>>(w1, w2, wmax);
    k_wquant<<<dim3(WELEM / 256, 2), 256, 0, stream>>>(w1, w2, pat1, pat2, wmax, wq1, wq2);

    // h1 = act_quant(bn1(x)) -> transposed codes
    k_stats<<<128, 256, 0, stream>>>(x, stats1);
    k_actT<<<256, 256, 0, stream>>>(x, stats1, gamma1, beta1, hbufT);
    // conv1 -> d_out (fp32 scratch)
    k_conv<<<dim3(BATCH, 2), 256, 0, stream>>>(hbufT, wq1, pat1, (const float*)0, out);
    // h2 = act_quant(bn2(out1))
    k_stats<<<128, 256, 0, stream>>>(out, stats2);
    k_actT<<<256, 256, 0, stream>>>(out, stats2, gamma2, beta2, hbufT);
    // conv2 + residual -> d_out
    k_conv<<<dim3(BATCH, 2), 256, 0, stream>>>(hbufT, wq2, pat2, x, out);
}

// Round 3
// 70.195 us; speedup vs baseline: 4.2064x; 1.2078x over previous
//
#include <hip/hip_runtime.h>
#include <math.h>

#define BATCH 128
#define CHN   128
#define HW    256            // 16*16
#define PLANE (CHN*HW)       // 32768
#define WELEM (CHN*CHN*9)    // 147456

using int4v  = __attribute__((ext_vector_type(4))) int;
using int16v = __attribute__((ext_vector_type(16))) int;

// ---- ws layout (bytes) ----
// 0     : wmax partials (144 floats: 72 per tensor)
// 1024  : stats1 final (mean,istd interleaved, 256 f)
// 2048  : stats1 partials (512 f: [c*2+half]*2 + {sum,sumsq})
// 4096  : gS  (128 i64) conv1 per-channel exact sums
// 5120  : gQ  (128 i64) conv1 per-channel exact sum-squares
// 8192  : wq1 i8, MFMA-fragment order, 147456 B
// 155648: wq2 i8, 147456 B
// 303104: hbufT u8 [n][p][c], 4194304 B

__device__ __forceinline__ float wave_sum(float v) {
    #pragma unroll
    for (int off = 32; off; off >>= 1) v += __shfl_down(v, off, 64);
    return v;
}
__device__ __forceinline__ float wave_max(float v) {
    #pragma unroll
    for (int off = 32; off; off >>= 1) v = fmaxf(v, __shfl_down(v, off, 64));
    return v;
}

// blocks 0..255: stats1 partials (c = b>>1, n-half = b&1)
// blocks 256..399: max|tanh(w)| partials (72 per tensor)
extern "C" __global__ void __launch_bounds__(256)
k_pre1(const float* __restrict__ x,
       const float* __restrict__ w1, const float* __restrict__ w2,
       float* __restrict__ s1part, float* __restrict__ wmaxp) {
    int b = blockIdx.x;
    int t = threadIdx.x;
    int lane = t & 63, wid = t >> 6;
    __shared__ float ls[8];

    if (b < 256) {
        int c = b >> 1, half = b & 1;
        const float* p = x + (size_t)(half * 64) * PLANE + c * HW + t;
        float s = 0.f, s2 = 0.f;
        #pragma unroll 4
        for (int n = 0; n < 64; ++n) {
            float v = p[n * PLANE];
            s += v; s2 += v * v;
        }
        s = wave_sum(s); s2 = wave_sum(s2);
        if (lane == 0) { ls[wid] = s; ls[4 + wid] = s2; }
        __syncthreads();
        if (t == 0) {
            s1part[b * 2]     = ls[0] + ls[1] + ls[2] + ls[3];
            s1part[b * 2 + 1] = ls[4] + ls[5] + ls[6] + ls[7];
        }
    } else {
        int i2 = b - 256;
        int y = (i2 >= 72) ? 1 : 0;
        int blk = i2 - y * 72;
        const float* w = y ? w2 : w1;
        int i = blk * 2048 + t;
        float m = 0.f;
        #pragma unroll
        for (int k = 0; k < 8; ++k)
            m = fmaxf(m, fabsf(tanhf(w[i + k * 256])));
        m = wave_max(m);
        if (lane == 0) ls[wid] = m;
        __syncthreads();
        if (t == 0)
            wmaxp[y * 72 + blk] = fmaxf(fmaxf(ls[0], ls[1]), fmaxf(ls[2], ls[3]));
    }
}

// blocks x<576: DoReFa weight quant + pattern mask -> i8 MFMA-fragment order
// block x==576,y==0: combine stats1 partials; zero gS/gQ
extern "C" __global__ void __launch_bounds__(256)
k_pre2(const float* __restrict__ w1, const float* __restrict__ w2,
       const float* __restrict__ pat1, const float* __restrict__ pat2,
       const float* __restrict__ wmaxp, const float* __restrict__ s1part,
       float* __restrict__ stats1,
       unsigned long long* __restrict__ gS, unsigned long long* __restrict__ gQ,
       signed char* __restrict__ wq1, signed char* __restrict__ wq2) {
    int t = threadIdx.x;
    if (blockIdx.x == 576) {
        if (blockIdx.y == 0) {
            if (t < 128) {
                float S  = s1part[(2 * t) * 2]     + s1part[(2 * t + 1) * 2];
                float S2 = s1part[(2 * t) * 2 + 1] + s1part[(2 * t + 1) * 2 + 1];
                float mean = S * (1.f / 32768.f);
                float var  = S2 * (1.f / 32768.f) - mean * mean;
                stats1[2 * t]     = mean;
                stats1[2 * t + 1] = 1.0f / sqrtf(var + 1e-5f);
            } else {
                gS[t - 128] = 0ull;
                gQ[t - 128] = 0ull;
            }
        }
        return;
    }
    int y = blockIdx.y;
    const float* w   = y ? w2 : w1;
    const float* pat = y ? pat2 : pat1;
    signed char* wq  = y ? wq2 : wq1;

    __shared__ float lm[72];
    if (t < 72) lm[t] = wmaxp[y * 72 + t];
    __syncthreads();
    float M = lm[0];
    #pragma unroll
    for (int k = 1; k < 72; ++k) M = fmaxf(M, lm[k]);

    int i = blockIdx.x * 256 + t;  // 0 .. 147455
    int j = i & 15;
    int c = i >> 4;
    int ocb = (c >= 4608) ? 1 : 0;
    int rem = c - ocb * 4608;
    int tap = rem >> 9;
    int q   = (rem >> 7) & 3;
    int m   = (rem >> 6) & 1;
    int hq  = (rem >> 5) & 1;
    int l31 = rem & 31;
    int oc = ocb * 64 + m * 32 + l31;
    int ic = q * 32 + hq * 16 + j;
    float tv = tanhf(w[(oc * CHN + ic) * 9 + tap]);
    float tn = tv / (2.0f * M) + 0.5f;
    int mq = (int)rintf(tn * 15.f);
    mq = mq < 0 ? 0 : (mq > 15 ? 15 : mq);
    int qv = 2 * mq - 15;
    if (pat[tap] == 0.f) qv = 0;
    wq[i] = (signed char)qv;
}

// BN + clip + 4-bit quant + transpose to [n][p][c] u8 codes.
// stats from float (mean,istd) pairs OR exact integer sums (gS/gQ non-null).
extern "C" __global__ void __launch_bounds__(256)
k_actT(const float* __restrict__ src, const float* __restrict__ statsF,
       const unsigned long long* __restrict__ gS, const unsigned long long* __restrict__ gQ,
       const float* __restrict__ gamma, const float* __restrict__ beta,
       unsigned char* __restrict__ dstT) {
    int b = blockIdx.x;
    int n = b >> 1, half = b & 1;
    int t = threadIdx.x;
    __shared__ unsigned int tmp[32 * 129];
    __shared__ float2 tab[128];

    if (t < 128) {
        float sc, sh;
        if (gS) {
            long long S = (long long)gS[t];
            long long Q = (long long)gQ[t];
            double mean = (double)S * (1.0 / (32768.0 * 225.0));
            double ex2  = (double)Q * (1.0 / (32768.0 * 225.0 * 225.0));
            double var  = ex2 - mean * mean;
            float istd = (float)(1.0 / sqrt(var + 1e-5));
            sc = istd * gamma[t];
            sh = beta[t] - (float)mean * sc;
        } else {
            float mean = statsF[2 * t], istd = statsF[2 * t + 1];
            sc = istd * gamma[t];
            sh = beta[t] - mean * sc;
        }
        tab[t] = make_float2(sc, sh);
    }
    __syncthreads();

    const float* sp = src + (size_t)n * PLANE + half * 128;
    #pragma unroll 4
    for (int j = 0; j < 16; ++j) {
        int id = j * 256 + t;            // c = id>>5 (0..127), p4 = id&31
        int cch = id >> 5, p4 = id & 31;
        float sc = tab[cch].x, sh = tab[cch].y;
        float4 v = *(const float4*)(sp + cch * HW + p4 * 4);
        unsigned q0 = (unsigned)(int)rintf(fminf(fmaxf(v.x * sc + sh, 0.f), 1.f) * 15.f);
        unsigned q1 = (unsigned)(int)rintf(fminf(fmaxf(v.y * sc + sh, 0.f), 1.f) * 15.f);
        unsigned q2 = (unsigned)(int)rintf(fminf(fmaxf(v.z * sc + sh, 0.f), 1.f) * 15.f);
        unsigned q3 = (unsigned)(int)rintf(fminf(fmaxf(v.w * sc + sh, 0.f), 1.f) * 15.f);
        tmp[p4 * 129 + cch] = q0 | (q1 << 8) | (q2 << 16) | (q3 << 24);
    }
    __syncthreads();

    unsigned char* dp = dstT + (size_t)n * PLANE + half * 128 * CHN;
    {
        int p4 = t & 31, c0 = (t >> 5) << 4;
        unsigned w[16];
        #pragma unroll
        for (int k = 0; k < 16; ++k) w[k] = tmp[p4 * 129 + c0 + k];
        #pragma unroll
        for (int pp = 0; pp < 4; ++pp) {
            int s = pp * 8;
            int4v o;
            o.x = (int)(((w[0] >> s) & 255u) | (((w[1] >> s) & 255u) << 8) |
                        (((w[2] >> s) & 255u) << 16) | (((w[3] >> s) & 255u) << 24));
            o.y = (int)(((w[4] >> s) & 255u) | (((w[5] >> s) & 255u) << 8) |
                        (((w[6] >> s) & 255u) << 16) | (((w[7] >> s) & 255u) << 24));
            o.z = (int)(((w[8] >> s) & 255u) | (((w[9] >> s) & 255u) << 8) |
                        (((w[10] >> s) & 255u) << 16) | (((w[11] >> s) & 255u) << 24));
            o.w = (int)(((w[12] >> s) & 255u) | (((w[13] >> s) & 255u) << 8) |
                        (((w[14] >> s) & 255u) << 16) | (((w[15] >> s) & 255u) << 24));
            *(int4v*)(dp + (p4 * 4 + pp) * 128 + c0) = o;
        }
    }
}

// i8 MFMA conv: block = (image, oc-half), 4 waves, wave tile = 64oc x 64px.
// If gS non-null: also accumulate exact per-channel sum / sum-sq (integer atomics).
extern "C" __global__ void __launch_bounds__(256, 1)
k_conv(const unsigned char* __restrict__ actT,   // [n][p][c] codes
       const signed char*  __restrict__ wq,      // fragment-ordered i8
       const float* __restrict__ pat,
       const float* __restrict__ xres,
       unsigned long long* __restrict__ gS, unsigned long long* __restrict__ gQ,
       float* __restrict__ out) {
    int n = blockIdx.x, ocb = blockIdx.y;
    int t = threadIdx.x;
    int lane = t & 63, wid = t >> 6;
    int l31 = lane & 31, hq = lane >> 5;

    __shared__ __align__(16) unsigned char lds[41472 + 73728];
    unsigned char* A = lds;            // padded act [r=18*18][128], swizzled
    unsigned char* W = lds + 41472;    // fragment-ordered weights (this oc-half)

    int4v z; z.x = 0; z.y = 0; z.z = 0; z.w = 0;
    for (int i = t; i < 2592; i += 256) *(int4v*)(A + i * 16) = z;
    __syncthreads();

    {
        const int4v* wsrc = (const int4v*)(wq + (size_t)ocb * 73728);
        int4v* wdst = (int4v*)W;
        #pragma unroll
        for (int j = 0; j < 18; ++j) wdst[j * 256 + t] = wsrc[j * 256 + t];
    }
    {
        const unsigned char* ap = actT + (size_t)n * PLANE;
        #pragma unroll
        for (int j = 0; j < 8; ++j) {
            int id = j * 256 + t;
            int p = id >> 3, c0 = (id & 7) << 4;
            int r = ((p >> 4) + 1) * 18 + (p & 15) + 1;
            int4v v = *(const int4v*)(ap + p * 128 + c0);
            *(int4v*)(A + r * 128 + (c0 ^ ((r & 7) << 4))) = v;
        }
    }
    __syncthreads();

    int16v acc[2][2];
    #pragma unroll
    for (int m = 0; m < 2; ++m)
        #pragma unroll
        for (int nn = 0; nn < 2; ++nn)
            #pragma unroll
            for (int e = 0; e < 16; ++e) acc[m][nn][e] = 0;

    int p0 = wid * 64 + l31;
    int h0 = p0 >> 4, w0c = p0 & 15;
    int p1 = p0 + 32;
    int h1 = p1 >> 4, w1c = p1 & 15;
    int cbase = hq * 16;

    #pragma unroll
    for (int tap = 0; tap < 9; ++tap) {
        if (pat[tap] != 0.f) {
            int dy = tap / 3, dx = tap % 3;
            int r0 = (h0 + dy) * 18 + (w0c + dx);
            int r1 = (h1 + dy) * 18 + (w1c + dx);
            int b0base = r0 * 128 + (cbase ^ ((r0 & 7) << 4));
            int b1base = r1 * 128 + (cbase ^ ((r1 & 7) << 4));
            const unsigned char* wt = W + tap * 8192 + lane * 16;
            #pragma unroll
            for (int q = 0; q < 4; ++q) {
                int4v a0 = *(const int4v*)(wt + q * 2048);
                int4v a1 = *(const int4v*)(wt + q * 2048 + 1024);
                int4v b0 = *(const int4v*)(A + (b0base ^ (q << 5)));
                int4v b1 = *(const int4v*)(A + (b1base ^ (q << 5)));
                acc[0][0] = __builtin_amdgcn_mfma_i32_32x32x32_i8(a0, b0, acc[0][0], 0, 0, 0);
                acc[0][1] = __builtin_amdgcn_mfma_i32_32x32x32_i8(a0, b1, acc[0][1], 0, 0, 0);
                acc[1][0] = __builtin_amdgcn_mfma_i32_32x32x32_i8(a1, b0, acc[1][0], 0, 0, 0);
                acc[1][1] = __builtin_amdgcn_mfma_i32_32x32x32_i8(a1, b1, acc[1][1], 0, 0, 0);
            }
        }
    }

    float* ob = out + ((size_t)n * CHN + ocb * 64) * HW;
    const float* xb = xres ? xres + ((size_t)n * CHN + ocb * 64) * HW : (const float*)0;
    #pragma unroll
    for (int m = 0; m < 2; ++m)
        #pragma unroll
        for (int nn = 0; nn < 2; ++nn) {
            int p = wid * 64 + nn * 32 + l31;
            #pragma unroll
            for (int e = 0; e < 16; ++e) {
                int row = (e & 3) + 8 * (e >> 2) + 4 * hq;
                int idx = (m * 32 + row) * HW + p;
                float v = (float)acc[m][nn][e] * (1.f / 225.f);
                if (xb) v += xb[idx];
                ob[idx] = v;
            }
        }

    // fused exact BN2 stats: per-channel sum / sum-sq of the integer conv outputs
    if (gS) {
        __syncthreads();   // all waves done with LDS A/W reads
        int*       lsm = (int*)lds;               // [4][64]
        long long* lq  = (long long*)(lds + 1024); // [4][64]
        #pragma unroll
        for (int m = 0; m < 2; ++m) {
            #pragma unroll
            for (int e = 0; e < 16; ++e) {
                int a0 = acc[m][0][e], a1 = acc[m][1][e];
                int s = a0 + a1;
                long long qq = (long long)a0 * a0 + (long long)a1 * a1;
                #pragma unroll
                for (int off = 1; off < 32; off <<= 1) {
                    s  += __shfl_xor(s, off, 64);
                    qq += __shfl_xor(qq, off, 64);
                }
                if (l31 == 0) {
                    int ch = m * 32 + (e & 3) + 8 * (e >> 2) + 4 * hq;
                    lsm[wid * 64 + ch] = s;
                    lq [wid * 64 + ch] = qq;
                }
            }
        }
        __syncthreads();
        if (t < 64) {
            long long S = 0, Q = 0;
            #pragma unroll
            for (int w = 0; w < 4; ++w) { S += lsm[w * 64 + t]; Q += lq[w * 64 + t]; }
            atomicAdd(gS + ocb * 64 + t, (unsigned long long)S);
            atomicAdd(gQ + ocb * 64 + t, (unsigned long long)Q);
        }
    }
}

extern "C" void kernel_launch(void* const* d_in, const int* in_sizes, int n_in,
                              void* d_out, int out_size, void* d_ws, size_t ws_size,
                              hipStream_t stream) {
    const float* x      = (const float*)d_in[0];
    const float* gamma1 = (const float*)d_in[1];
    const float* beta1  = (const float*)d_in[2];
    const float* gamma2 = (const float*)d_in[3];
    const float* beta2  = (const float*)d_in[4];
    const float* w1     = (const float*)d_in[5];
    const float* w2     = (const float*)d_in[6];
    const float* pat1   = (const float*)d_in[7];
    const float* pat2   = (const float*)d_in[8];
    float* out = (float*)d_out;

    char* ws = (char*)d_ws;
    float* wmaxp     = (float*)(ws + 0);
    float* stats1    = (float*)(ws + 1024);
    float* s1part    = (float*)(ws + 2048);
    unsigned long long* gS = (unsigned long long*)(ws + 4096);
    unsigned long long* gQ = (unsigned long long*)(ws + 5120);
    signed char* wq1 = (signed char*)(ws + 8192);
    signed char* wq2 = (signed char*)(ws + 155648);
    unsigned char* hbufT = (unsigned char*)(ws + 303104);

    // stats1 partials + wmax partials (no memset, no atomics)
    k_pre1<<<400, 256, 0, stream>>>(x, w1, w2, s1part, wmaxp);
    // weight quant (both tensors) + stats1 combine + zero stats2 accumulators
    k_pre2<<<dim3(577, 2), 256, 0, stream>>>(w1, w2, pat1, pat2, wmaxp, s1part,
                                             stats1, gS, gQ, wq1, wq2);
    // h1 = act_quant(bn1(x)) -> transposed codes
    k_actT<<<256, 256, 0, stream>>>(x, stats1, nullptr, nullptr, gamma1, beta1, hbufT);
    // conv1 -> d_out (fp32 scratch) + exact BN2 stats
    k_conv<<<dim3(BATCH, 2), 256, 0, stream>>>(hbufT, wq1, pat1, (const float*)0, gS, gQ, out);
    // h2 = act_quant(bn2(out1)) using exact integer stats
    k_actT<<<256, 256, 0, stream>>>(out, nullptr, gS, gQ, gamma2, beta2, hbufT);
    // conv2 + residual -> d_out
    k_conv<<<dim3(BATCH, 2), 256, 0, stream>>>(hbufT, wq2, pat2, x,
                                               (unsigned long long*)0, (unsigned long long*)0, out);
}

// Round 4
// 55.257 us; speedup vs baseline: 5.3436x; 1.2703x over previous
//
#include <hip/hip_runtime.h>
#include <math.h>

#define BATCH 128
#define CHN   128
#define HW    256            // 16*16
#define PLANE (CHN*HW)       // 32768
#define WELEM (CHN*CHN*9)    // 147456

using int4v  = __attribute__((ext_vector_type(4))) int;
using int16v = __attribute__((ext_vector_type(16))) int;
typedef unsigned int u32;

// async global->LDS, 16B per lane, dest = wave-uniform base + lane*16
__device__ __forceinline__ void gload16(const void* g, void* l) {
    __builtin_amdgcn_global_load_lds((const __attribute__((address_space(1))) u32*)g,
                                     (__attribute__((address_space(3))) u32*)l, 16, 0, 0);
}

// ---- ws layout (bytes) ----
// 0     : wmax partials (144 floats)
// 1024  : stats1 final (mean,istd interleaved)
// 2048  : stats1 partials (512 f)
// 4096  : gS (128 i64)   5120 : gQ (128 i64)
// 8192  : wq1 i8 fragment order (4 x 36864 per ocq), 147456 B
// 155648: wq2 i8, 147456 B
// 303104: hbufT u8 [n][p][c0^swz(r(p))], 4194304 B

__device__ __forceinline__ float wave_sum(float v) {
    #pragma unroll
    for (int off = 32; off; off >>= 1) v += __shfl_down(v, off, 64);
    return v;
}
__device__ __forceinline__ float wave_max(float v) {
    #pragma unroll
    for (int off = 32; off; off >>= 1) v = fmaxf(v, __shfl_down(v, off, 64));
    return v;
}

// blocks 0..255: stats1 partials; blocks 256..399: max|tanh(w)| partials
extern "C" __global__ void __launch_bounds__(256)
k_pre1(const float* __restrict__ x,
       const float* __restrict__ w1, const float* __restrict__ w2,
       float* __restrict__ s1part, float* __restrict__ wmaxp) {
    int b = blockIdx.x;
    int t = threadIdx.x;
    int lane = t & 63, wid = t >> 6;
    __shared__ float ls[8];

    if (b < 256) {
        int c = b >> 1, half = b & 1;
        const float* p = x + (size_t)(half * 64) * PLANE + c * HW + t;
        float s = 0.f, s2 = 0.f;
        #pragma unroll 4
        for (int n = 0; n < 64; ++n) {
            float v = p[n * PLANE];
            s += v; s2 += v * v;
        }
        s = wave_sum(s); s2 = wave_sum(s2);
        if (lane == 0) { ls[wid] = s; ls[4 + wid] = s2; }
        __syncthreads();
        if (t == 0) {
            s1part[b * 2]     = ls[0] + ls[1] + ls[2] + ls[3];
            s1part[b * 2 + 1] = ls[4] + ls[5] + ls[6] + ls[7];
        }
    } else {
        int i2 = b - 256;
        int y = (i2 >= 72) ? 1 : 0;
        int blk = i2 - y * 72;
        const float* w = y ? w2 : w1;
        int i = blk * 2048 + t;
        float m = 0.f;
        #pragma unroll
        for (int k = 0; k < 8; ++k)
            m = fmaxf(m, fabsf(tanhf(w[i + k * 256])));
        m = wave_max(m);
        if (lane == 0) ls[wid] = m;
        __syncthreads();
        if (t == 0)
            wmaxp[y * 72 + blk] = fmaxf(fmaxf(ls[0], ls[1]), fmaxf(ls[2], ls[3]));
    }
}

// blocks x<576: weight quant -> i8 fragment order (per oc-quarter)
// block x==576,y==0: combine stats1; zero gS/gQ
extern "C" __global__ void __launch_bounds__(256)
k_pre2(const float* __restrict__ w1, const float* __restrict__ w2,
       const float* __restrict__ pat1, const float* __restrict__ pat2,
       const float* __restrict__ wmaxp, const float* __restrict__ s1part,
       float* __restrict__ stats1,
       unsigned long long* __restrict__ gS, unsigned long long* __restrict__ gQ,
       signed char* __restrict__ wq1, signed char* __restrict__ wq2) {
    int t = threadIdx.x;
    if (blockIdx.x == 576) {
        if (blockIdx.y == 0) {
            if (t < 128) {
                float S  = s1part[(2 * t) * 2]     + s1part[(2 * t + 1) * 2];
                float S2 = s1part[(2 * t) * 2 + 1] + s1part[(2 * t + 1) * 2 + 1];
                float mean = S * (1.f / 32768.f);
                float var  = S2 * (1.f / 32768.f) - mean * mean;
                stats1[2 * t]     = mean;
                stats1[2 * t + 1] = 1.0f / sqrtf(var + 1e-5f);
            } else {
                gS[t - 128] = 0ull;
                gQ[t - 128] = 0ull;
            }
        }
        return;
    }
    int y = blockIdx.y;
    const float* w   = y ? w2 : w1;
    const float* pat = y ? pat2 : pat1;
    signed char* wq  = y ? wq2 : wq1;

    __shared__ float lm[72];
    if (t < 72) lm[t] = wmaxp[y * 72 + t];
    __syncthreads();
    float M = lm[0];
    #pragma unroll
    for (int k = 1; k < 72; ++k) M = fmaxf(M, lm[k]);

    // byte i = ((ocq*2304 + tap*256 + q*64 + hq*32 + l31)*16 + j)
    // holds w_int[oc=ocq*32+l31][tap][ic=q*32+hq*16+j]
    int i = blockIdx.x * 256 + t;
    int j = i & 15;
    int c = i >> 4;
    int ocq = c / 2304;
    int rem = c - ocq * 2304;
    int tap = rem >> 8;
    int r2  = rem & 255;
    int q   = r2 >> 6;
    int hq  = (r2 >> 5) & 1;
    int l31 = r2 & 31;
    int oc = ocq * 32 + l31;
    int ic = q * 32 + hq * 16 + j;
    float tv = tanhf(w[(oc * CHN + ic) * 9 + tap]);
    float tn = tv / (2.0f * M) + 0.5f;
    int mq = (int)rintf(tn * 15.f);
    mq = mq < 0 ? 0 : (mq > 15 ? 15 : mq);
    int qv = 2 * mq - 15;
    if (pat[tap] == 0.f) qv = 0;
    wq[i] = (signed char)qv;
}

// BN + clip + 4-bit quant + transpose to [n][p][c] codes, PRE-SWIZZLED:
// 16B chunk c0 of pixel p stored at (p*128 + (c0 ^ ((r(p)&7)<<4)))
extern "C" __global__ void __launch_bounds__(256)
k_actT(const float* __restrict__ src, const float* __restrict__ statsF,
       const unsigned long long* __restrict__ gS, const unsigned long long* __restrict__ gQ,
       const float* __restrict__ gamma, const float* __restrict__ beta,
       unsigned char* __restrict__ dstT) {
    int b = blockIdx.x;
    int n = b >> 1, half = b & 1;
    int t = threadIdx.x;
    __shared__ u32 tmp[32 * 129];
    __shared__ float2 tab[128];

    if (t < 128) {
        float sc, sh;
        if (gS) {
            long long S = (long long)gS[t];
            long long Q = (long long)gQ[t];
            double mean = (double)S * (1.0 / (32768.0 * 225.0));
            double ex2  = (double)Q * (1.0 / (32768.0 * 225.0 * 225.0));
            double var  = ex2 - mean * mean;
            float istd = (float)(1.0 / sqrt(var + 1e-5));
            sc = istd * gamma[t];
            sh = beta[t] - (float)mean * sc;
        } else {
            float mean = statsF[2 * t], istd = statsF[2 * t + 1];
            sc = istd * gamma[t];
            sh = beta[t] - mean * sc;
        }
        tab[t] = make_float2(sc, sh);
    }
    __syncthreads();

    const float* sp = src + (size_t)n * PLANE + half * 128;
    #pragma unroll 4
    for (int j = 0; j < 16; ++j) {
        int id = j * 256 + t;            // cch = id>>5, p4 = id&31
        int cch = id >> 5, p4 = id & 31;
        float sc = tab[cch].x, sh = tab[cch].y;
        float4 v = *(const float4*)(sp + cch * HW + p4 * 4);
        unsigned q0 = (unsigned)(int)rintf(fminf(fmaxf(v.x * sc + sh, 0.f), 1.f) * 15.f);
        unsigned q1 = (unsigned)(int)rintf(fminf(fmaxf(v.y * sc + sh, 0.f), 1.f) * 15.f);
        unsigned q2 = (unsigned)(int)rintf(fminf(fmaxf(v.z * sc + sh, 0.f), 1.f) * 15.f);
        unsigned q3 = (unsigned)(int)rintf(fminf(fmaxf(v.w * sc + sh, 0.f), 1.f) * 15.f);
        tmp[p4 * 129 + cch] = q0 | (q1 << 8) | (q2 << 16) | (q3 << 24);
    }
    __syncthreads();

    // store: 8 lanes cover one 128B [p][c] row -> fully coalesced
    unsigned char* dp = dstT + (size_t)n * PLANE + half * 128 * CHN;
    {
        int p4 = t >> 3;              // 0..31
        int c0 = (t & 7) * 16;        // word chunk base (bytes)
        u32 w[16];
        #pragma unroll
        for (int k = 0; k < 16; ++k) w[k] = tmp[p4 * 129 + c0 + k];
        #pragma unroll
        for (int pp = 0; pp < 4; ++pp) {
            int p = p4 * 4 + pp;                   // local pixel in half
            int pg = half * 128 + p;               // global pixel in image
            int r = ((pg >> 4) + 1) * 18 + (pg & 15) + 1;
            int xr = (r & 7) << 4;
            int s = pp * 8;
            int4v o;
            o.x = (int)(((w[0] >> s) & 255u) | (((w[1] >> s) & 255u) << 8) |
                        (((w[2] >> s) & 255u) << 16) | (((w[3] >> s) & 255u) << 24));
            o.y = (int)(((w[4] >> s) & 255u) | (((w[5] >> s) & 255u) << 8) |
                        (((w[6] >> s) & 255u) << 16) | (((w[7] >> s) & 255u) << 24));
            o.z = (int)(((w[8] >> s) & 255u) | (((w[9] >> s) & 255u) << 8) |
                        (((w[10] >> s) & 255u) << 16) | (((w[11] >> s) & 255u) << 24));
            o.w = (int)(((w[12] >> s) & 255u) | (((w[13] >> s) & 255u) << 8) |
                        (((w[14] >> s) & 255u) << 16) | (((w[15] >> s) & 255u) << 24));
            *(int4v*)(dp + p * 128 + (c0 ^ xr)) = o;
        }
    }
}

// i8 MFMA conv: block = (image, oc-quarter 32oc), 4 waves x 64px, 2 blocks/CU
extern "C" __global__ void __launch_bounds__(256, 2)
k_conv(const unsigned char* __restrict__ actT,   // pre-swizzled [n][p][c] codes
       const signed char*  __restrict__ wq,      // fragment-ordered i8
       const float* __restrict__ pat,
       const float* __restrict__ xres,
       unsigned long long* __restrict__ gS, unsigned long long* __restrict__ gQ,
       float* __restrict__ out) {
    int n = blockIdx.x, ocq = blockIdx.y;
    int t = threadIdx.x;
    int lane = t & 63, wid = t >> 6;
    int l31 = lane & 31, hq = lane >> 5;

    __shared__ __align__(16) unsigned char lds[41472 + 36864];
    unsigned char* A = lds;            // [r=18*18][128] swizzled act
    unsigned char* W = lds + 41472;    // [tap][q][lane][16] weights

    // zero only the halo (68 rows); interior fully overwritten by DMA
    int4v z; z.x = 0; z.y = 0; z.z = 0; z.w = 0;
    for (int cidx = t; cidx < 544; cidx += 256) {
        int hrow = cidx >> 3, ch = cidx & 7;
        int r;
        if (hrow < 18) r = hrow;
        else if (hrow < 36) r = 306 + (hrow - 18);
        else { int h2 = hrow - 36; r = (1 + (h2 & 15)) * 18 + ((h2 >> 4) ? 17 : 0); }
        *(int4v*)(A + r * 128 + ch * 16) = z;
    }

    // stage weights (linear, 9 x 4KB)
    {
        const unsigned char* wsrc = (const unsigned char*)wq + (size_t)ocq * 36864;
        #pragma unroll
        for (int it = 0; it < 9; ++it)
            gload16(wsrc + it * 4096 + wid * 1024 + (lane << 4),
                    W + it * 4096 + wid * 1024);
    }
    // stage act: source pre-swizzled -> linear LDS dest (wave-uniform 1KB rows)
    {
        const unsigned char* ap = actT + (size_t)n * PLANE;
        #pragma unroll
        for (int j = 0; j < 8; ++j) {
            int p0w = j * 32 + wid * 8;
            int r0 = ((p0w >> 4) + 1) * 18 + (p0w & 15) + 1;
            gload16(ap + p0w * 128 + (lane << 4), A + r0 * 128);
        }
    }

    bool pf[9];
    #pragma unroll
    for (int j = 0; j < 9; ++j) pf[j] = (pat[j] != 0.f);

    __syncthreads();

    int16v acc0, acc1;
    #pragma unroll
    for (int e = 0; e < 16; ++e) { acc0[e] = 0; acc1[e] = 0; }

    int p0 = wid * 64 + l31;
    int h0 = p0 >> 4, w0c = p0 & 15;
    int p1 = p0 + 32;
    int h1 = p1 >> 4, w1c = p1 & 15;
    int cbase = hq * 16;

    #pragma unroll
    for (int tap = 0; tap < 9; ++tap) {
        if (pf[tap]) {
            int dy = tap / 3, dx = tap % 3;
            int r0 = (h0 + dy) * 18 + (w0c + dx);
            int r1 = (h1 + dy) * 18 + (w1c + dx);
            int b0base = r0 * 128 + (cbase ^ ((r0 & 7) << 4));
            int b1base = r1 * 128 + (cbase ^ ((r1 & 7) << 4));
            const unsigned char* wt = W + tap * 4096 + (lane << 4);
            #pragma unroll
            for (int q = 0; q < 4; ++q) {
                int4v a0 = *(const int4v*)(wt + q * 1024);
                int4v b0 = *(const int4v*)(A + (b0base ^ (q << 5)));
                int4v b1 = *(const int4v*)(A + (b1base ^ (q << 5)));
                acc0 = __builtin_amdgcn_mfma_i32_32x32x32_i8(a0, b0, acc0, 0, 0, 0);
                acc1 = __builtin_amdgcn_mfma_i32_32x32x32_i8(a0, b1, acc1, 0, 0, 0);
            }
        }
    }

    float* ob = out + ((size_t)n * CHN + ocq * 32) * HW;
    const float* xb = xres ? xres + ((size_t)n * CHN + ocq * 32) * HW : (const float*)0;
    #pragma unroll
    for (int e = 0; e < 16; ++e) {
        int row = (e & 3) + 8 * (e >> 2) + 4 * hq;
        int idx0 = row * HW + wid * 64 + l31;
        float v0 = (float)acc0[e] * (1.f / 225.f);
        float v1 = (float)acc1[e] * (1.f / 225.f);
        if (xb) { v0 += xb[idx0]; v1 += xb[idx0 + 32]; }
        ob[idx0]      = v0;
        ob[idx0 + 32] = v1;
    }

    // fused exact BN2 stats (conv1 only)
    if (gS) {
        __syncthreads();
        int*       lsm = (int*)lds;                 // [4][32]
        long long* lq  = (long long*)(lds + 512);   // [4][32]
        #pragma unroll
        for (int e = 0; e < 16; ++e) {
            int a0 = acc0[e], a1 = acc1[e];
            int s = a0 + a1;
            long long qq = (long long)a0 * a0 + (long long)a1 * a1;
            #pragma unroll
            for (int off = 1; off < 32; off <<= 1) {
                s  += __shfl_xor(s, off, 64);
                qq += __shfl_xor(qq, off, 64);
            }
            if (l31 == 0) {
                int ch = (e & 3) + 8 * (e >> 2) + 4 * hq;
                lsm[wid * 32 + ch] = s;
                lq [wid * 32 + ch] = qq;
            }
        }
        __syncthreads();
        if (t < 32) {
            long long S = 0, Q = 0;
            #pragma unroll
            for (int w = 0; w < 4; ++w) { S += lsm[w * 32 + t]; Q += lq[w * 32 + t]; }
            atomicAdd(gS + ocq * 32 + t, (unsigned long long)S);
            atomicAdd(gQ + ocq * 32 + t, (unsigned long long)Q);
        }
    }
}

extern "C" void kernel_launch(void* const* d_in, const int* in_sizes, int n_in,
                              void* d_out, int out_size, void* d_ws, size_t ws_size,
                              hipStream_t stream) {
    const float* x      = (const float*)d_in[0];
    const float* gamma1 = (const float*)d_in[1];
    const float* beta1  = (const float*)d_in[2];
    const float* gamma2 = (const float*)d_in[3];
    const float* beta2  = (const float*)d_in[4];
    const float* w1     = (const float*)d_in[5];
    const float* w2     = (const float*)d_in[6];
    const float* pat1   = (const float*)d_in[7];
    const float* pat2   = (const float*)d_in[8];
    float* out = (float*)d_out;

    char* ws = (char*)d_ws;
    float* wmaxp     = (float*)(ws + 0);
    float* stats1    = (float*)(ws + 1024);
    float* s1part    = (float*)(ws + 2048);
    unsigned long long* gS = (unsigned long long*)(ws + 4096);
    unsigned long long* gQ = (unsigned long long*)(ws + 5120);
    signed char* wq1 = (signed char*)(ws + 8192);
    signed char* wq2 = (signed char*)(ws + 155648);
    unsigned char* hbufT = (unsigned char*)(ws + 303104);

    k_pre1<<<400, 256, 0, stream>>>(x, w1, w2, s1part, wmaxp);
    k_pre2<<<dim3(577, 2), 256, 0, stream>>>(w1, w2, pat1, pat2, wmaxp, s1part,
                                             stats1, gS, gQ, wq1, wq2);
    k_actT<<<256, 256, 0, stream>>>(x, stats1, nullptr, nullptr, gamma1, beta1, hbufT);
    k_conv<<<dim3(BATCH, 4), 256, 0, stream>>>(hbufT, wq1, pat1, (const float*)0, gS, gQ, out);
    k_actT<<<256, 256, 0, stream>>>(out, nullptr, gS, gQ, gamma2, beta2, hbufT);
    k_conv<<<dim3(BATCH, 4), 256, 0, stream>>>(hbufT, wq2, pat2, x,
                                               (unsigned long long*)0, (unsigned long long*)0, out);
}

// Round 6
// 55.088 us; speedup vs baseline: 5.3599x; 1.0031x over previous
//
#include <hip/hip_runtime.h>
#include <hip/hip_cooperative_groups.h>
#include <math.h>

namespace cg = cooperative_groups;

#define BATCH 128
#define CHN   128
#define HW    256            // 16*16
#define PLANE (CHN*HW)       // 32768
#define WELEM (CHN*CHN*9)    // 147456

using int4v  = __attribute__((ext_vector_type(4))) int;
using int16v = __attribute__((ext_vector_type(16))) int;
typedef unsigned int u32;

// async global->LDS, 16B per lane, dest = wave-uniform base + lane*16
__device__ __forceinline__ void gload16(const void* g, void* l) {
    __builtin_amdgcn_global_load_lds((const __attribute__((address_space(1))) u32*)g,
                                     (__attribute__((address_space(3))) u32*)l, 16, 0, 0);
}

// ---- ws layout (bytes) ----
// 0     : wmax partials (144 f)
// 1024  : stats1 final (256 f)        [fallback path only]
// 2048  : stats1 partials (512 f)
// 4096  : gS (128 i64)   5120 : gQ (128 i64)
// 8192  : wq1 i8 fragment order, 147456 B
// 155648: wq2 i8, 147456 B
// 303104: hbufT u8 [n][p][c0^swz(r(p))], 4194304 B

__device__ __forceinline__ float wave_sum(float v) {
    #pragma unroll
    for (int off = 32; off; off >>= 1) v += __shfl_down(v, off, 64);
    return v;
}
__device__ __forceinline__ float wave_max(float v) {
    #pragma unroll
    for (int off = 32; off; off >>= 1) v = fmaxf(v, __shfl_down(v, off, 64));
    return v;
}

// ==================== FALLBACK KERNELS (round-4, proven) ====================

extern "C" __global__ void __launch_bounds__(256)
k_pre1(const float* __restrict__ x,
       const float* __restrict__ w1, const float* __restrict__ w2,
       float* __restrict__ s1part, float* __restrict__ wmaxp) {
    int b = blockIdx.x;
    int t = threadIdx.x;
    int lane = t & 63, wid = t >> 6;
    __shared__ float ls[8];

    if (b < 256) {
        int c = b >> 1, half = b & 1;
        const float* p = x + (size_t)(half * 64) * PLANE + c * HW + t;
        float s = 0.f, s2 = 0.f;
        #pragma unroll 4
        for (int n = 0; n < 64; ++n) {
            float v = p[n * PLANE];
            s += v; s2 += v * v;
        }
        s = wave_sum(s); s2 = wave_sum(s2);
        if (lane == 0) { ls[wid] = s; ls[4 + wid] = s2; }
        __syncthreads();
        if (t == 0) {
            s1part[b * 2]     = ls[0] + ls[1] + ls[2] + ls[3];
            s1part[b * 2 + 1] = ls[4] + ls[5] + ls[6] + ls[7];
        }
    } else {
        int i2 = b - 256;
        int y = (i2 >= 72) ? 1 : 0;
        int blk = i2 - y * 72;
        const float* w = y ? w2 : w1;
        int i = blk * 2048 + t;
        float m = 0.f;
        #pragma unroll
        for (int k = 0; k < 8; ++k)
            m = fmaxf(m, fabsf(tanhf(w[i + k * 256])));
        m = wave_max(m);
        if (lane == 0) ls[wid] = m;
        __syncthreads();
        if (t == 0)
            wmaxp[y * 72 + blk] = fmaxf(fmaxf(ls[0], ls[1]), fmaxf(ls[2], ls[3]));
    }
}

extern "C" __global__ void __launch_bounds__(256)
k_pre2(const float* __restrict__ w1, const float* __restrict__ w2,
       const float* __restrict__ pat1, const float* __restrict__ pat2,
       const float* __restrict__ wmaxp, const float* __restrict__ s1part,
       float* __restrict__ stats1,
       unsigned long long* __restrict__ gS, unsigned long long* __restrict__ gQ,
       signed char* __restrict__ wq1, signed char* __restrict__ wq2) {
    int t = threadIdx.x;
    if (blockIdx.x == 576) {
        if (blockIdx.y == 0) {
            if (t < 128) {
                float S  = s1part[(2 * t) * 2]     + s1part[(2 * t + 1) * 2];
                float S2 = s1part[(2 * t) * 2 + 1] + s1part[(2 * t + 1) * 2 + 1];
                float mean = S * (1.f / 32768.f);
                float var  = S2 * (1.f / 32768.f) - mean * mean;
                stats1[2 * t]     = mean;
                stats1[2 * t + 1] = 1.0f / sqrtf(var + 1e-5f);
            } else {
                gS[t - 128] = 0ull;
                gQ[t - 128] = 0ull;
            }
        }
        return;
    }
    int y = blockIdx.y;
    const float* w   = y ? w2 : w1;
    const float* pat = y ? pat2 : pat1;
    signed char* wq  = y ? wq2 : wq1;

    __shared__ float lm[72];
    if (t < 72) lm[t] = wmaxp[y * 72 + t];
    __syncthreads();
    float M = lm[0];
    #pragma unroll
    for (int k = 1; k < 72; ++k) M = fmaxf(M, lm[k]);

    int i = blockIdx.x * 256 + t;
    int j = i & 15;
    int c = i >> 4;
    int ocq = c / 2304;
    int rem = c - ocq * 2304;
    int tap = rem >> 8;
    int r2  = rem & 255;
    int q   = r2 >> 6;
    int hq  = (r2 >> 5) & 1;
    int l31 = r2 & 31;
    int oc = ocq * 32 + l31;
    int ic = q * 32 + hq * 16 + j;
    float tv = tanhf(w[(oc * CHN + ic) * 9 + tap]);
    float tn = tv / (2.0f * M) + 0.5f;
    int mq = (int)rintf(tn * 15.f);
    mq = mq < 0 ? 0 : (mq > 15 ? 15 : mq);
    int qv = 2 * mq - 15;
    if (pat[tap] == 0.f) qv = 0;
    wq[i] = (signed char)qv;
}

extern "C" __global__ void __launch_bounds__(256)
k_actT(const float* __restrict__ src, const float* __restrict__ statsF,
       const unsigned long long* __restrict__ gS, const unsigned long long* __restrict__ gQ,
       const float* __restrict__ gamma, const float* __restrict__ beta,
       unsigned char* __restrict__ dstT) {
    int b = blockIdx.x;
    int n = b >> 1, half = b & 1;
    int t = threadIdx.x;
    __shared__ u32 tmp[32 * 129];
    __shared__ float2 tab[128];

    if (t < 128) {
        float sc, sh;
        if (gS) {
            long long S = (long long)gS[t];
            long long Q = (long long)gQ[t];
            double mean = (double)S * (1.0 / (32768.0 * 225.0));
            double ex2  = (double)Q * (1.0 / (32768.0 * 225.0 * 225.0));
            double var  = ex2 - mean * mean;
            float istd = (float)(1.0 / sqrt(var + 1e-5));
            sc = istd * gamma[t];
            sh = beta[t] - (float)mean * sc;
        } else {
            float mean = statsF[2 * t], istd = statsF[2 * t + 1];
            sc = istd * gamma[t];
            sh = beta[t] - mean * sc;
        }
        tab[t] = make_float2(sc, sh);
    }
    __syncthreads();

    const float* sp = src + (size_t)n * PLANE + half * 128;
    #pragma unroll 4
    for (int j = 0; j < 16; ++j) {
        int id = j * 256 + t;
        int cch = id >> 5, p4 = id & 31;
        float sc = tab[cch].x, sh = tab[cch].y;
        float4 v = *(const float4*)(sp + cch * HW + p4 * 4);
        unsigned q0 = (unsigned)(int)rintf(fminf(fmaxf(v.x * sc + sh, 0.f), 1.f) * 15.f);
        unsigned q1 = (unsigned)(int)rintf(fminf(fmaxf(v.y * sc + sh, 0.f), 1.f) * 15.f);
        unsigned q2 = (unsigned)(int)rintf(fminf(fmaxf(v.z * sc + sh, 0.f), 1.f) * 15.f);
        unsigned q3 = (unsigned)(int)rintf(fminf(fmaxf(v.w * sc + sh, 0.f), 1.f) * 15.f);
        tmp[p4 * 129 + cch] = q0 | (q1 << 8) | (q2 << 16) | (q3 << 24);
    }
    __syncthreads();

    unsigned char* dp = dstT + (size_t)n * PLANE + half * 128 * CHN;
    {
        int p4 = t >> 3;
        int c0 = (t & 7) * 16;
        u32 w[16];
        #pragma unroll
        for (int k = 0; k < 16; ++k) w[k] = tmp[p4 * 129 + c0 + k];
        #pragma unroll
        for (int pp = 0; pp < 4; ++pp) {
            int p = p4 * 4 + pp;
            int pg = half * 128 + p;
            int r = ((pg >> 4) + 1) * 18 + (pg & 15) + 1;
            int xr = (r & 7) << 4;
            int s = pp * 8;
            int4v o;
            o.x = (int)(((w[0] >> s) & 255u) | (((w[1] >> s) & 255u) << 8) |
                        (((w[2] >> s) & 255u) << 16) | (((w[3] >> s) & 255u) << 24));
            o.y = (int)(((w[4] >> s) & 255u) | (((w[5] >> s) & 255u) << 8) |
                        (((w[6] >> s) & 255u) << 16) | (((w[7] >> s) & 255u) << 24));
            o.z = (int)(((w[8] >> s) & 255u) | (((w[9] >> s) & 255u) << 8) |
                        (((w[10] >> s) & 255u) << 16) | (((w[11] >> s) & 255u) << 24));
            o.w = (int)(((w[12] >> s) & 255u) | (((w[13] >> s) & 255u) << 8) |
                        (((w[14] >> s) & 255u) << 16) | (((w[15] >> s) & 255u) << 24));
            *(int4v*)(dp + p * 128 + (c0 ^ xr)) = o;
        }
    }
}

extern "C" __global__ void __launch_bounds__(256, 2)
k_conv(const unsigned char* __restrict__ actT,
       const signed char*  __restrict__ wq,
       const float* __restrict__ pat,
       const float* __restrict__ xres,
       unsigned long long* __restrict__ gS, unsigned long long* __restrict__ gQ,
       float* __restrict__ out) {
    int n = blockIdx.x, ocq = blockIdx.y;
    int t = threadIdx.x;
    int lane = t & 63, wid = t >> 6;
    int l31 = lane & 31, hq = lane >> 5;

    __shared__ __align__(16) unsigned char lds[41472 + 36864];
    unsigned char* A = lds;
    unsigned char* W = lds + 41472;

    int4v z; z.x = 0; z.y = 0; z.z = 0; z.w = 0;
    for (int cidx = t; cidx < 544; cidx += 256) {
        int hrow = cidx >> 3, ch = cidx & 7;
        int r;
        if (hrow < 18) r = hrow;
        else if (hrow < 36) r = 306 + (hrow - 18);
        else { int h2 = hrow - 36; r = (1 + (h2 & 15)) * 18 + ((h2 >> 4) ? 17 : 0); }
        *(int4v*)(A + r * 128 + ch * 16) = z;
    }

    {
        const unsigned char* wsrc = (const unsigned char*)wq + (size_t)ocq * 36864;
        #pragma unroll
        for (int it = 0; it < 9; ++it)
            gload16(wsrc + it * 4096 + wid * 1024 + (lane << 4),
                    W + it * 4096 + wid * 1024);
    }
    {
        const unsigned char* ap = actT + (size_t)n * PLANE;
        #pragma unroll
        for (int j = 0; j < 8; ++j) {
            int p0w = j * 32 + wid * 8;
            int r0 = ((p0w >> 4) + 1) * 18 + (p0w & 15) + 1;
            gload16(ap + p0w * 128 + (lane << 4), A + r0 * 128);
        }
    }

    bool pf[9];
    #pragma unroll
    for (int j = 0; j < 9; ++j) pf[j] = (pat[j] != 0.f);

    __syncthreads();

    int16v acc0, acc1;
    #pragma unroll
    for (int e = 0; e < 16; ++e) { acc0[e] = 0; acc1[e] = 0; }

    int p0 = wid * 64 + l31;
    int h0 = p0 >> 4, w0c = p0 & 15;
    int p1 = p0 + 32;
    int h1 = p1 >> 4, w1c = p1 & 15;
    int cbase = hq * 16;

    #pragma unroll
    for (int tap = 0; tap < 9; ++tap) {
        if (pf[tap]) {
            int dy = tap / 3, dx = tap % 3;
            int r0 = (h0 + dy) * 18 + (w0c + dx);
            int r1 = (h1 + dy) * 18 + (w1c + dx);
            int b0base = r0 * 128 + (cbase ^ ((r0 & 7) << 4));
            int b1base = r1 * 128 + (cbase ^ ((r1 & 7) << 4));
            const unsigned char* wt = W + tap * 4096 + (lane << 4);
            #pragma unroll
            for (int q = 0; q < 4; ++q) {
                int4v a0 = *(const int4v*)(wt + q * 1024);
                int4v b0 = *(const int4v*)(A + (b0base ^ (q << 5)));
                int4v b1 = *(const int4v*)(A + (b1base ^ (q << 5)));
                acc0 = __builtin_amdgcn_mfma_i32_32x32x32_i8(a0, b0, acc0, 0, 0, 0);
                acc1 = __builtin_amdgcn_mfma_i32_32x32x32_i8(a0, b1, acc1, 0, 0, 0);
            }
        }
    }

    float* ob = out + ((size_t)n * CHN + ocq * 32) * HW;
    const float* xb = xres ? xres + ((size_t)n * CHN + ocq * 32) * HW : (const float*)0;
    #pragma unroll
    for (int e = 0; e < 16; ++e) {
        int row = (e & 3) + 8 * (e >> 2) + 4 * hq;
        int idx0 = row * HW + wid * 64 + l31;
        float v0 = (float)acc0[e] * (1.f / 225.f);
        float v1 = (float)acc1[e] * (1.f / 225.f);
        if (xb) { v0 += xb[idx0]; v1 += xb[idx0 + 32]; }
        ob[idx0]      = v0;
        ob[idx0 + 32] = v1;
    }

    if (gS) {
        __syncthreads();
        int*       lsm = (int*)lds;
        long long* lq  = (long long*)(lds + 512);
        #pragma unroll
        for (int e = 0; e < 16; ++e) {
            int a0 = acc0[e], a1 = acc1[e];
            int s = a0 + a1;
            long long qq = (long long)a0 * a0 + (long long)a1 * a1;
            #pragma unroll
            for (int off = 1; off < 32; off <<= 1) {
                s  += __shfl_xor(s, off, 64);
                qq += __shfl_xor(qq, off, 64);
            }
            if (l31 == 0) {
                int ch = (e & 3) + 8 * (e >> 2) + 4 * hq;
                lsm[wid * 32 + ch] = s;
                lq [wid * 32 + ch] = qq;
            }
        }
        __syncthreads();
        if (t < 32) {
            long long S = 0, Q = 0;
            #pragma unroll
            for (int w = 0; w < 4; ++w) { S += lsm[w * 32 + t]; Q += lq[w * 32 + t]; }
            atomicAdd(gS + ocq * 32 + t, (unsigned long long)S);
            atomicAdd(gQ + ocq * 32 + t, (unsigned long long)Q);
        }
    }
}

// ==================== COOPERATIVE KERNELS ====================

extern "C" __global__ void __launch_bounds__(256, 2)
k_front(const float* __restrict__ x,
        const float* __restrict__ w1, const float* __restrict__ w2,
        const float* __restrict__ pat1, const float* __restrict__ pat2,
        const float* __restrict__ gamma1, const float* __restrict__ beta1,
        float* __restrict__ s1part, float* __restrict__ wmaxp,
        unsigned long long* __restrict__ gS, unsigned long long* __restrict__ gQ,
        signed char* __restrict__ wq1, signed char* __restrict__ wq2,
        unsigned char* __restrict__ hbufT) {
    int b = blockIdx.x;
    int t = threadIdx.x;
    int lane = t & 63, wid = t >> 6;
    __shared__ float ls[8];
    __shared__ u32 tmp[32 * 129];
    __shared__ float2 tab[128];
    __shared__ float lmx[144];
    __shared__ float Ms[2];

    if (b < 256) {
        int c = b >> 1, half = b & 1;
        const float* p = x + (size_t)(half * 64) * PLANE + c * HW + t;
        float s = 0.f, s2 = 0.f;
        #pragma unroll 4
        for (int n = 0; n < 64; ++n) {
            float v = p[n * PLANE];
            s += v; s2 += v * v;
        }
        s = wave_sum(s); s2 = wave_sum(s2);
        if (lane == 0) { ls[wid] = s; ls[4 + wid] = s2; }
        __syncthreads();
        if (t == 0) {
            s1part[b * 2]     = ls[0] + ls[1] + ls[2] + ls[3];
            s1part[b * 2 + 1] = ls[4] + ls[5] + ls[6] + ls[7];
        }
    } else if (b < 400) {
        int i2 = b - 256;
        int y = (i2 >= 72) ? 1 : 0;
        int blk = i2 - y * 72;
        const float* w = y ? w2 : w1;
        int i = blk * 2048 + t;
        float m = 0.f;
        #pragma unroll
        for (int k = 0; k < 8; ++k)
            m = fmaxf(m, fabsf(tanhf(w[i + k * 256])));
        m = wave_max(m);
        if (lane == 0) ls[wid] = m;
        __syncthreads();
        if (t == 0)
            wmaxp[y * 72 + blk] = fmaxf(fmaxf(ls[0], ls[1]), fmaxf(ls[2], ls[3]));
    }

    cg::this_grid().sync();

    if (b < 256) {
        int n = b >> 1, half = b & 1;
        if (t < 128) {
            float S  = s1part[(2 * t) * 2]     + s1part[(2 * t + 1) * 2];
            float S2 = s1part[(2 * t) * 2 + 1] + s1part[(2 * t + 1) * 2 + 1];
            float mean = S * (1.f / 32768.f);
            float var  = S2 * (1.f / 32768.f) - mean * mean;
            float istd = 1.0f / sqrtf(var + 1e-5f);
            float sc = istd * gamma1[t];
            float sh = beta1[t] - mean * sc;
            tab[t] = make_float2(sc, sh);
        }
        __syncthreads();

        const float* sp = x + (size_t)n * PLANE + half * 128;
        #pragma unroll 4
        for (int j = 0; j < 16; ++j) {
            int id = j * 256 + t;
            int cch = id >> 5, p4 = id & 31;
            float sc = tab[cch].x, sh = tab[cch].y;
            float4 v = *(const float4*)(sp + cch * HW + p4 * 4);
            unsigned q0 = (unsigned)(int)rintf(fminf(fmaxf(v.x * sc + sh, 0.f), 1.f) * 15.f);
            unsigned q1 = (unsigned)(int)rintf(fminf(fmaxf(v.y * sc + sh, 0.f), 1.f) * 15.f);
            unsigned q2 = (unsigned)(int)rintf(fminf(fmaxf(v.z * sc + sh, 0.f), 1.f) * 15.f);
            unsigned q3 = (unsigned)(int)rintf(fminf(fmaxf(v.w * sc + sh, 0.f), 1.f) * 15.f);
            tmp[p4 * 129 + cch] = q0 | (q1 << 8) | (q2 << 16) | (q3 << 24);
        }
        __syncthreads();

        unsigned char* dp = hbufT + (size_t)n * PLANE + half * 128 * CHN;
        int p4 = t >> 3;
        int c0 = (t & 7) * 16;
        u32 w[16];
        #pragma unroll
        for (int k = 0; k < 16; ++k) w[k] = tmp[p4 * 129 + c0 + k];
        #pragma unroll
        for (int pp = 0; pp < 4; ++pp) {
            int p = p4 * 4 + pp;
            int pg = half * 128 + p;
            int r = ((pg >> 4) + 1) * 18 + (pg & 15) + 1;
            int xr = (r & 7) << 4;
            int s = pp * 8;
            int4v o;
            o.x = (int)(((w[0] >> s) & 255u) | (((w[1] >> s) & 255u) << 8) |
                        (((w[2] >> s) & 255u) << 16) | (((w[3] >> s) & 255u) << 24));
            o.y = (int)(((w[4] >> s) & 255u) | (((w[5] >> s) & 255u) << 8) |
                        (((w[6] >> s) & 255u) << 16) | (((w[7] >> s) & 255u) << 24));
            o.z = (int)(((w[8] >> s) & 255u) | (((w[9] >> s) & 255u) << 8) |
                        (((w[10] >> s) & 255u) << 16) | (((w[11] >> s) & 255u) << 24));
            o.w = (int)(((w[12] >> s) & 255u) | (((w[13] >> s) & 255u) << 8) |
                        (((w[14] >> s) & 255u) << 16) | (((w[15] >> s) & 255u) << 24));
            *(int4v*)(dp + p * 128 + (c0 ^ xr)) = o;
        }
    } else {
        for (int i = t; i < 144; i += 256) lmx[i] = wmaxp[i];
        __syncthreads();
        if (t == 0) {
            float m = lmx[0];
            for (int k = 1; k < 72; ++k) m = fmaxf(m, lmx[k]);
            Ms[0] = m;
            m = lmx[72];
            for (int k = 73; k < 144; ++k) m = fmaxf(m, lmx[k]);
            Ms[1] = m;
        }
        __syncthreads();
        if (b == 511 && t < 128) { gS[t] = 0ull; gQ[t] = 0ull; }

        for (int idx = (b - 256) * 256 + t; idx < 2 * WELEM; idx += 65536) {
            int y = (idx >= WELEM) ? 1 : 0;
            int i = idx - y * WELEM;
            const float* w   = y ? w2 : w1;
            const float* pat = y ? pat2 : pat1;
            signed char* wq  = y ? wq2 : wq1;
            float M = Ms[y];
            int j = i & 15;
            int c = i >> 4;
            int ocq = c / 2304;
            int rem = c - ocq * 2304;
            int tap = rem >> 8;
            int r2  = rem & 255;
            int q   = r2 >> 6;
            int hq  = (r2 >> 5) & 1;
            int l31 = r2 & 31;
            int oc = ocq * 32 + l31;
            int ic = q * 32 + hq * 16 + j;
            float tv = tanhf(w[(oc * CHN + ic) * 9 + tap]);
            float tn = tv / (2.0f * M) + 0.5f;
            int mq = (int)rintf(tn * 15.f);
            mq = mq < 0 ? 0 : (mq > 15 ? 15 : mq);
            int qv = 2 * mq - 15;
            if (pat[tap] == 0.f) qv = 0;
            wq[i] = (signed char)qv;
        }
    }
}

// conv1 -> exact stats -> quantize act2 in place -> conv2  (LDS 59904 < 64KB)
extern "C" __global__ void __launch_bounds__(256, 2)
k_conv_all(unsigned char* __restrict__ hb,
           const signed char* __restrict__ wq1, const signed char* __restrict__ wq2,
           const float* __restrict__ pat1, const float* __restrict__ pat2,
           const float* __restrict__ gamma2, const float* __restrict__ beta2,
           unsigned long long* __restrict__ gS, unsigned long long* __restrict__ gQ,
           const float* __restrict__ x, float* __restrict__ out) {
    int n = blockIdx.x, ocq = blockIdx.y;
    int t = threadIdx.x;
    int lane = t & 63, wid = t >> 6;
    int l31 = lane & 31, hq = lane >> 5;

    __shared__ __align__(16) unsigned char lds[41472 + 18432];
    unsigned char* A  = lds;            // [r=18*18][128] swizzled act codes
    unsigned char* Wh = lds + 41472;    // one K-half of weights [tap][qq][lane][16]

    int4v z; z.x = 0; z.y = 0; z.z = 0; z.w = 0;
    for (int cidx = t; cidx < 544; cidx += 256) {
        int hrow = cidx >> 3, ch = cidx & 7;
        int r;
        if (hrow < 18) r = hrow;
        else if (hrow < 36) r = 306 + (hrow - 18);
        else { int h2 = hrow - 36; r = (1 + (h2 & 15)) * 18 + ((h2 >> 4) ? 17 : 0); }
        *(int4v*)(A + r * 128 + ch * 16) = z;
    }

    unsigned char* ap = hb + (size_t)n * PLANE;

    int p0 = wid * 64 + l31;
    int h0 = p0 >> 4, w0c = p0 & 15;
    int p1 = p0 + 32;
    int h1 = p1 >> 4, w1c = p1 & 15;
    int cbase = hq * 16;

    int16v acc0, acc1;

    #pragma unroll
    for (int ph = 0; ph < 2; ++ph) {
        const signed char* wq = ph ? wq2 : wq1;
        const float* pat      = ph ? pat2 : pat1;
        const unsigned char* wsrc = (const unsigned char*)wq + (size_t)ocq * 36864;

        // stage act codes
        #pragma unroll
        for (int j = 0; j < 8; ++j) {
            int p0w = j * 32 + wid * 8;
            int r0 = ((p0w >> 4) + 1) * 18 + (p0w & 15) + 1;
            gload16(ap + p0w * 128 + (lane << 4), A + r0 * 128);
        }
        // stage W K-half 0 (q = 0,1): 18 x 1KB chunks
        for (int it = wid; it < 18; it += 4)
            gload16(wsrc + (it >> 1) * 4096 + (it & 1) * 1024 + (lane << 4),
                    Wh + (it >> 1) * 2048 + (it & 1) * 1024);

        bool pf[9];
        #pragma unroll
        for (int j = 0; j < 9; ++j) pf[j] = (pat[j] != 0.f);

        __syncthreads();

        #pragma unroll
        for (int e = 0; e < 16; ++e) { acc0[e] = 0; acc1[e] = 0; }

        #pragma unroll
        for (int tap = 0; tap < 9; ++tap) {
            if (pf[tap]) {
                int dy = tap / 3, dx = tap % 3;
                int r0 = (h0 + dy) * 18 + (w0c + dx);
                int r1 = (h1 + dy) * 18 + (w1c + dx);
                int b0base = r0 * 128 + (cbase ^ ((r0 & 7) << 4));
                int b1base = r1 * 128 + (cbase ^ ((r1 & 7) << 4));
                const unsigned char* wt = Wh + tap * 2048 + (lane << 4);
                #pragma unroll
                for (int qq = 0; qq < 2; ++qq) {
                    int4v a0 = *(const int4v*)(wt + qq * 1024);
                    int4v b0 = *(const int4v*)(A + (b0base ^ (qq << 5)));
                    int4v b1 = *(const int4v*)(A + (b1base ^ (qq << 5)));
                    acc0 = __builtin_amdgcn_mfma_i32_32x32x32_i8(a0, b0, acc0, 0, 0, 0);
                    acc1 = __builtin_amdgcn_mfma_i32_32x32x32_i8(a0, b1, acc1, 0, 0, 0);
                }
            }
        }
        __syncthreads();   // all waves done reading Wh half 0
        // stage W K-half 1 (q = 2,3)
        for (int it = wid; it < 18; it += 4)
            gload16(wsrc + (it >> 1) * 4096 + 2048 + (it & 1) * 1024 + (lane << 4),
                    Wh + (it >> 1) * 2048 + (it & 1) * 1024);
        __syncthreads();

        #pragma unroll
        for (int tap = 0; tap < 9; ++tap) {
            if (pf[tap]) {
                int dy = tap / 3, dx = tap % 3;
                int r0 = (h0 + dy) * 18 + (w0c + dx);
                int r1 = (h1 + dy) * 18 + (w1c + dx);
                int b0base = r0 * 128 + (cbase ^ ((r0 & 7) << 4));
                int b1base = r1 * 128 + (cbase ^ ((r1 & 7) << 4));
                const unsigned char* wt = Wh + tap * 2048 + (lane << 4);
                #pragma unroll
                for (int qq = 0; qq < 2; ++qq) {
                    int q = 2 + qq;
                    int4v a0 = *(const int4v*)(wt + qq * 1024);
                    int4v b0 = *(const int4v*)(A + (b0base ^ (q << 5)));
                    int4v b1 = *(const int4v*)(A + (b1base ^ (q << 5)));
                    acc0 = __builtin_amdgcn_mfma_i32_32x32x32_i8(a0, b0, acc0, 0, 0, 0);
                    acc1 = __builtin_amdgcn_mfma_i32_32x32x32_i8(a0, b1, acc1, 0, 0, 0);
                }
            }
        }

        if (ph == 0) {
            __syncthreads();                         // done reading A/Wh
            int*       lsm  = (int*)Wh;              // [4][32]
            long long* lq   = (long long*)(Wh + 512);
            float2*    tabL = (float2*)(Wh + 2048);  // [32]
            #pragma unroll
            for (int e = 0; e < 16; ++e) {
                int a0 = acc0[e], a1 = acc1[e];
                int s = a0 + a1;
                long long qq = (long long)a0 * a0 + (long long)a1 * a1;
                #pragma unroll
                for (int off = 1; off < 32; off <<= 1) {
                    s  += __shfl_xor(s, off, 64);
                    qq += __shfl_xor(qq, off, 64);
                }
                if (l31 == 0) {
                    int ch = (e & 3) + 8 * (e >> 2) + 4 * hq;
                    lsm[wid * 32 + ch] = s;
                    lq [wid * 32 + ch] = qq;
                }
            }
            __syncthreads();
            if (t < 32) {
                long long S = 0, Q = 0;
                #pragma unroll
                for (int w = 0; w < 4; ++w) { S += lsm[w * 32 + t]; Q += lq[w * 32 + t]; }
                atomicAdd(gS + ocq * 32 + t, (unsigned long long)S);
                atomicAdd(gQ + ocq * 32 + t, (unsigned long long)Q);
            }

            cg::this_grid().sync();

            if (t < 32) {
                int ch = ocq * 32 + t;
                long long S = (long long)gS[ch];
                long long Q = (long long)gQ[ch];
                double mean = (double)S * (1.0 / (32768.0 * 225.0));
                double ex2  = (double)Q * (1.0 / (32768.0 * 225.0 * 225.0));
                double var  = ex2 - mean * mean;
                float istd = (float)(1.0 / sqrt(var + 1e-5));
                float sc = istd * gamma2[ch];
                float sh = beta2[ch] - (float)mean * sc;
                tabL[t] = make_float2(sc, sh);
            }
            __syncthreads();

            #pragma unroll
            for (int half2 = 0; half2 < 2; ++half2) {
                const int16v& ac = half2 ? acc1 : acc0;
                int p = half2 ? p1 : p0;
                u32 wrd[4];
                #pragma unroll
                for (int k = 0; k < 4; ++k) {
                    u32 pk = 0;
                    #pragma unroll
                    for (int e2 = 0; e2 < 4; ++e2) {
                        int e = 4 * k + e2;
                        int row = (e & 3) + 8 * k + 4 * hq;
                        float2 ss = tabL[row];
                        float v = (float)ac[e] * (1.f / 225.f);
                        u32 q = (u32)(int)rintf(fminf(fmaxf(v * ss.x + ss.y, 0.f), 1.f) * 15.f);
                        pk |= q << (8 * e2);
                    }
                    wrd[k] = pk;
                }
                u32 prt[4];
                #pragma unroll
                for (int k = 0; k < 4; ++k) prt[k] = __shfl_xor(wrd[k], 32, 64);
                int4v o;
                if (hq == 0) { o.x = (int)wrd[0]; o.y = (int)prt[0]; o.z = (int)wrd[1]; o.w = (int)prt[1]; }
                else         { o.x = (int)prt[2]; o.y = (int)wrd[2]; o.z = (int)prt[3]; o.w = (int)wrd[3]; }
                int c0 = ocq * 32 + (hq ? 16 : 0);
                int r = ((p >> 4) + 1) * 18 + (p & 15) + 1;
                int xr = (r & 7) << 4;
                *(int4v*)(hb + (size_t)n * PLANE + p * 128 + (c0 ^ xr)) = o;
            }

            cg::this_grid().sync();
        }
    }

    float* ob = out + ((size_t)n * CHN + ocq * 32) * HW;
    const float* xb = x + ((size_t)n * CHN + ocq * 32) * HW;
    #pragma unroll
    for (int e = 0; e < 16; ++e) {
        int row = (e & 3) + 8 * (e >> 2) + 4 * hq;
        int idx0 = row * HW + wid * 64 + l31;
        ob[idx0]      = (float)acc0[e] * (1.f / 225.f) + xb[idx0];
        ob[idx0 + 32] = (float)acc1[e] * (1.f / 225.f) + xb[idx0 + 32];
    }
}

extern "C" void kernel_launch(void* const* d_in, const int* in_sizes, int n_in,
                              void* d_out, int out_size, void* d_ws, size_t ws_size,
                              hipStream_t stream) {
    const float* x      = (const float*)d_in[0];
    const float* gamma1 = (const float*)d_in[1];
    const float* beta1  = (const float*)d_in[2];
    const float* gamma2 = (const float*)d_in[3];
    const float* beta2  = (const float*)d_in[4];
    const float* w1     = (const float*)d_in[5];
    const float* w2     = (const float*)d_in[6];
    const float* pat1   = (const float*)d_in[7];
    const float* pat2   = (const float*)d_in[8];
    float* out = (float*)d_out;

    char* ws = (char*)d_ws;
    float* wmaxp     = (float*)(ws + 0);
    float* stats1    = (float*)(ws + 1024);
    float* s1part    = (float*)(ws + 2048);
    unsigned long long* gS = (unsigned long long*)(ws + 4096);
    unsigned long long* gQ = (unsigned long long*)(ws + 5120);
    signed char* wq1 = (signed char*)(ws + 8192);
    signed char* wq2 = (signed char*)(ws + 155648);
    unsigned char* hbufT = (unsigned char*)(ws + 303104);

    // deterministic host-side gate: coop only if validator will accept both grids
    int occF = 0, occC = 0;
    bool coop =
        hipOccupancyMaxActiveBlocksPerMultiprocessor(&occF, (const void*)k_front, 256, 0) == hipSuccess &&
        hipOccupancyMaxActiveBlocksPerMultiprocessor(&occC, (const void*)k_conv_all, 256, 0) == hipSuccess &&
        occF >= 2 && occC >= 2;

    bool frontDone = false;
    if (coop) {
        void* argsF[] = { (void*)&x, (void*)&w1, (void*)&w2, (void*)&pat1, (void*)&pat2,
                          (void*)&gamma1, (void*)&beta1, (void*)&s1part, (void*)&wmaxp,
                          (void*)&gS, (void*)&gQ, (void*)&wq1, (void*)&wq2, (void*)&hbufT };
        frontDone = hipLaunchCooperativeKernel((const void*)k_front, dim3(512), dim3(256),
                                               argsF, 0, stream) == hipSuccess;
        if (!frontDone) coop = false;
    }
    if (!frontDone) {
        k_pre1<<<400, 256, 0, stream>>>(x, w1, w2, s1part, wmaxp);
        k_pre2<<<dim3(577, 2), 256, 0, stream>>>(w1, w2, pat1, pat2, wmaxp, s1part,
                                                 stats1, gS, gQ, wq1, wq2);
        k_actT<<<256, 256, 0, stream>>>(x, stats1, nullptr, nullptr, gamma1, beta1, hbufT);
    }

    bool convDone = false;
    if (coop) {
        void* argsC[] = { (void*)&hbufT, (void*)&wq1, (void*)&wq2, (void*)&pat1, (void*)&pat2,
                          (void*)&gamma2, (void*)&beta2, (void*)&gS, (void*)&gQ,
                          (void*)&x, (void*)&out };
        convDone = hipLaunchCooperativeKernel((const void*)k_conv_all, dim3(128, 4), dim3(256),
                                              argsC, 0, stream) == hipSuccess;
    }
    if (!convDone) {
        k_conv<<<dim3(BATCH, 4), 256, 0, stream>>>(hbufT, wq1, pat1, (const float*)0, gS, gQ, out);
        k_actT<<<256, 256, 0, stream>>>(out, nullptr, gS, gQ, gamma2, beta2, hbufT);
        k_conv<<<dim3(BATCH, 4), 256, 0, stream>>>(hbufT, wq2, pat2, x,
                                                   (unsigned long long*)0, (unsigned long long*)0, out);
    }
}